// Round 5
// baseline (1206.902 us; speedup 1.0000x reference)
//
#include <hip/hip_runtime.h>

#define S 512
#define NB 8          // batch
#define KT 128        // W rows per block
#define JT 32         // j-chunk per pipeline stage

// Copy the untouched region: out[b,r,c] = x[b,r,c] for r+c >= S.
__global__ __launch_bounds__(256) void tail_copy_kernel(const float* __restrict__ x,
                                                        float* __restrict__ out) {
  int idx = blockIdx.x * 256 + threadIdx.x;
  int c = idx & (S - 1);
  int r = (idx >> 9) & (S - 1);
  if (r + c >= S) out[idx] = x[idx];
}

// Barrier-free structure: thread pair owns one W row end-to-end.
//   - D (<=16 KB) staged once in LDS; the ONLY __syncthreads in the kernel.
//   - Thread streams its half of row k from global into a 2-deep register
//     pipeline and FMAs against broadcast LDS reads of D. W never touches LDS,
//     there is no per-tile barrier, no cross-wave reduction (just shfl_xor(1)).
//   - Rows k>i retire right after the staging barrier (self-balancing);
//     i = 511-bx dispatches big diagonals first (LPT backfill).
__global__ __launch_bounds__(256, 6) void diag_linear_kernel(const float* __restrict__ x,
                                                             const float* __restrict__ W,
                                                             const float* __restrict__ bias,
                                                             float* __restrict__ out) {
  // Dl[j][b]: gathered diagonal of x (16 KB). Compute reads are 2-address
  // broadcasts (h=0/1 halves) -> free per m136.
  __shared__ __align__(16) float DlBuf[S * NB];

  const int i  = (S - 1) - (int)blockIdx.x;  // big diagonals first
  const int k0 = (int)blockIdx.y * KT;
  if (k0 > i) return;                        // uniform exit, before the barrier

  const int tid  = threadIdx.x;
  const int jend = (i + JT) & ~(JT - 1);     // roundup(i+1, 32)
  const int T    = jend >> 5;                // pipeline stages (>=1)

  // ---- stage D: Dl[j][b] = x[b, j, i-j] for j<=i, else 0 ----
  for (int idx = tid; idx < jend * NB; idx += 256) {
    const int j = idx >> 3;
    const int b = idx & 7;
    DlBuf[idx] = (j <= i) ? x[b * (S * S) + j * S + (i - j)] : 0.0f;
  }
  __syncthreads();                           // the only barrier

  // ---- row ownership: thread t -> row kl = t>>1, 16-float half h = t&1 ----
  const int kl = tid >> 1;
  const int h  = tid & 1;
  const int k  = k0 + kl;
  if (k > i) return;                         // dead rows retire immediately

  // W[i,k,j]=0 in memory for j>i, so reading up to jend (32-rounded) is safe.
  const float* wrow = W + ((size_t)i * S + k) * S + (h << 4);

  float acc[NB];
#pragma unroll
  for (int b = 0; b < NB; ++b) acc[b] = 0.0f;

  // ---- 2-deep register prefetch: group = 4 dwordx4 = this thread's 16 floats
  // of one 32-j chunk (j in [32t+16h, 32t+16h+16)).
  float4 v[2][4];
#define LOAD_GRP(g, t)                                                         \
  {                                                                            \
    const float* p = wrow + ((t) << 5);                                        \
    v[g][0] = *(const float4*)(p);                                             \
    v[g][1] = *(const float4*)(p + 4);                                         \
    v[g][2] = *(const float4*)(p + 8);                                         \
    v[g][3] = *(const float4*)(p + 12);                                        \
  }

  LOAD_GRP(0, 0)
  if (T > 1) LOAD_GRP(1, 1)

  for (int t = 0; t < T; ++t) {
    const int g  = t & 1;
    const int j0 = (t << 5) + (h << 4);
#pragma unroll
    for (int q = 0; q < 4; ++q) {
      const float wq[4] = {v[g][q].x, v[g][q].y, v[g][q].z, v[g][q].w};
#pragma unroll
      for (int e = 0; e < 4; ++e) {
        const int j = j0 + (q << 2) + e;
        const float4 dA = *(const float4*)&DlBuf[j * NB];      // broadcast
        const float4 dB = *(const float4*)&DlBuf[j * NB + 4];  // broadcast
        const float w = wq[e];
        acc[0] = fmaf(w, dA.x, acc[0]);
        acc[1] = fmaf(w, dA.y, acc[1]);
        acc[2] = fmaf(w, dA.z, acc[2]);
        acc[3] = fmaf(w, dA.w, acc[3]);
        acc[4] = fmaf(w, dB.x, acc[4]);
        acc[5] = fmaf(w, dB.y, acc[5]);
        acc[6] = fmaf(w, dB.z, acc[6]);
        acc[7] = fmaf(w, dB.w, acc[7]);
      }
    }
    const int tn = t + 2;
    if (tn < T) LOAD_GRP(g, tn)
  }

  // ---- pair reduction: partner (tid^1) holds the other j-half of row k ----
#pragma unroll
  for (int b = 0; b < NB; ++b) acc[b] += __shfl_xor(acc[b], 1);

  // ---- epilogue: bias + scatter out[b, i-k, k]; each half-thread writes 4 b ----
  const float bv = bias[i * S + k];
  const int r = i - k;
#pragma unroll
  for (int bq = 0; bq < 4; ++bq) {
    const int b = (h << 2) + bq;
    out[b * (S * S) + r * S + k] = acc[b] + bv;
  }
}

extern "C" void kernel_launch(void* const* d_in, const int* in_sizes, int n_in,
                              void* d_out, int out_size, void* d_ws, size_t ws_size,
                              hipStream_t stream) {
  const float* x    = (const float*)d_in[0];
  const float* W    = (const float*)d_in[1];
  const float* bias = (const float*)d_in[2];
  float* out = (float*)d_out;

  (void)d_ws; (void)ws_size; (void)in_sizes; (void)n_in; (void)out_size;

  tail_copy_kernel<<<dim3((NB * S * S) / 256), 256, 0, stream>>>(x, out);
  diag_linear_kernel<<<dim3(S, S / KT), 256, 0, stream>>>(x, W, bias, out);
}

// Round 6
// 1182.962 us; speedup vs baseline: 1.0202x; 1.0202x over previous
//
#include <hip/hip_runtime.h>

#define S 512
#define NB 8          // batch
#define KT 128        // W rows per block (2 threads/row * 256 threads)
#define JT 32         // j-chunk per pipeline stage

// d_ws layout: xd  = ws[0, S*S*NB)            -- xd[i][j][b], 8.4 MB
//              wsout = ws[S*S*NB, 2*S*S*NB)   -- wsout[i][k][b], 8.4 MB

// Copy the untouched region: out[b,r,c] = x[b,r,c] for r+c >= S. Coalesced.
__global__ __launch_bounds__(256) void tail_copy_kernel(const float* __restrict__ x,
                                                        float* __restrict__ out) {
  int idx = blockIdx.x * 256 + threadIdx.x;
  int c = idx & (S - 1);
  int r = (idx >> 9) & (S - 1);
  if (r + c >= S) out[idx] = x[idx];
}

// K1: do the anti-diagonal gather of x exactly once.
// xd[i][j][b] = x[b, j, i-j] for j<=i, 0 for j in (i, roundup32(i+1)).
// Reads are scattered 4B (x is L3-resident, 8.4 MB); writes fully coalesced.
__global__ __launch_bounds__(256) void gather_x_kernel(const float* __restrict__ x,
                                                       float* __restrict__ xd) {
  const int i = (int)blockIdx.x;
  const int jend = (i + JT) & ~(JT - 1);
  float* dst = xd + (size_t)i * (S * NB);
  for (int idx = threadIdx.x; idx < jend * NB; idx += 256) {
    const int j = idx >> 3;
    const int b = idx & 7;
    dst[idx] = (j <= i) ? x[b * (S * S) + j * S + (i - j)] : 0.0f;
  }
}

// K2: the hot kernel — now touches ONLY coalesced/contiguous addresses.
// Thread pair owns W row k end-to-end: stream row halves from global through a
// 2-deep register pipeline, FMA against broadcast LDS reads of D, shfl_xor(1)
// pair-reduce, write 32B-contiguous result vectors to wsout[i][k][b].
__global__ __launch_bounds__(256, 6) void diag_linear_kernel(const float* __restrict__ xd,
                                                             const float* __restrict__ W,
                                                             const float* __restrict__ bias,
                                                             float* __restrict__ wsout) {
  __shared__ __align__(16) float DlBuf[S * NB];   // D[j][b], 16 KB

  const int i  = (S - 1) - (int)blockIdx.x;  // big diagonals first (LPT backfill)
  const int k0 = (int)blockIdx.y * KT;
  if (k0 > i) return;                        // uniform exit, before the barrier

  const int tid  = threadIdx.x;
  const int jend = (i + JT) & ~(JT - 1);     // roundup(i+1, 32)
  const int T    = jend >> 5;                // pipeline stages (>=1)

  // ---- stage D from xd: fully coalesced float4 copy ----
  {
    const float4* src = (const float4*)(xd + (size_t)i * (S * NB));
    float4* dst = (float4*)DlBuf;
    const int n4 = (jend * NB) >> 2;         // <= 1024
    for (int idx = tid; idx < n4; idx += 256) dst[idx] = src[idx];
  }
  __syncthreads();                           // the only barrier

  // ---- row ownership: thread t -> row kl = t>>1, 16-float half h = t&1 ----
  const int kl = tid >> 1;
  const int h  = tid & 1;
  const int k  = k0 + kl;
  if (k > i) return;                         // dead rows retire immediately

  // W[i,k,j]=0 in memory for j>i, so reading up to jend (32-rounded) is safe.
  const float* wrow = W + ((size_t)i * S + k) * S + (h << 4);

  float acc[NB];
#pragma unroll
  for (int b = 0; b < NB; ++b) acc[b] = 0.0f;

  // ---- 2-deep register prefetch: group = 4 dwordx4 = this thread's 16 floats
  float4 v[2][4];
#define LOAD_GRP(g, t)                                                         \
  {                                                                            \
    const float* p = wrow + ((t) << 5);                                        \
    v[g][0] = *(const float4*)(p);                                             \
    v[g][1] = *(const float4*)(p + 4);                                         \
    v[g][2] = *(const float4*)(p + 8);                                         \
    v[g][3] = *(const float4*)(p + 12);                                        \
  }

  LOAD_GRP(0, 0)
  if (T > 1) LOAD_GRP(1, 1)

  for (int t = 0; t < T; ++t) {
    const int g  = t & 1;
    const int j0 = (t << 5) + (h << 4);
#pragma unroll
    for (int q = 0; q < 4; ++q) {
      const float wq[4] = {v[g][q].x, v[g][q].y, v[g][q].z, v[g][q].w};
#pragma unroll
      for (int e = 0; e < 4; ++e) {
        const int j = j0 + (q << 2) + e;
        const float4 dA = *(const float4*)&DlBuf[j * NB];      // broadcast
        const float4 dB = *(const float4*)&DlBuf[j * NB + 4];  // broadcast
        const float w = wq[e];
        acc[0] = fmaf(w, dA.x, acc[0]);
        acc[1] = fmaf(w, dA.y, acc[1]);
        acc[2] = fmaf(w, dA.z, acc[2]);
        acc[3] = fmaf(w, dA.w, acc[3]);
        acc[4] = fmaf(w, dB.x, acc[4]);
        acc[5] = fmaf(w, dB.y, acc[5]);
        acc[6] = fmaf(w, dB.z, acc[6]);
        acc[7] = fmaf(w, dB.w, acc[7]);
      }
    }
    const int tn = t + 2;
    if (tn < T) LOAD_GRP(g, tn)
  }

  // ---- pair reduction: partner (tid^1) holds the other j-half of row k ----
#pragma unroll
  for (int b = 0; b < NB; ++b) acc[b] += __shfl_xor(acc[b], 1);

  // ---- epilogue: bias + CONTIGUOUS write: wsout[i][k][4h..4h+3] ----
  const float bv = bias[i * S + k];
  *(float4*)&wsout[((size_t)i * S + k) * NB + (h << 2)] =
      make_float4(acc[(h << 2) + 0] + bv, acc[(h << 2) + 1] + bv,
                  acc[(h << 2) + 2] + bv, acc[(h << 2) + 3] + bv);
}

// K3: out[b,r,c] = wsout[r+c, c, b] for r+c < S.
// Thread owns one full 64B out line (16 c); writes coalesced full lines.
// Reads are scattered 4B but from the L2/L3-resident 8.4 MB wsout, and lanes
// b=0..7 (low bits of g) share each 64B wsout line per step -> requests merge.
__global__ __launch_bounds__(256) void scatter_out_kernel(const float* __restrict__ wsout,
                                                          float* __restrict__ out) {
  const int g  = (int)blockIdx.x * 256 + threadIdx.x;  // 131072 threads
  const int b  = g & 7;
  const int ch = (g >> 3) & 31;
  const int r  = g >> 8;
  const int c0 = ch << 4;
  if (r + c0 >= S) return;                   // tail region: tail_copy owns it
  const int nrem = S - r - c0;               // valid elements in this chunk
  const float* src = wsout + ((size_t)(r + c0) * S + c0) * NB + b;
  float* dst = out + (size_t)b * (S * S) + (size_t)r * S + c0;
  const size_t step = (size_t)(S + 1) * NB;  // per +1 in c: i and c both advance
  if (nrem >= 16) {
    float vv[16];
#pragma unroll
    for (int e = 0; e < 16; ++e) vv[e] = src[e * step];
#pragma unroll
    for (int q = 0; q < 4; ++q)
      ((float4*)dst)[q] = make_float4(vv[4 * q], vv[4 * q + 1],
                                      vv[4 * q + 2], vv[4 * q + 3]);
  } else {
    for (int e = 0; e < nrem; ++e) dst[e] = src[e * step];
  }
}

extern "C" void kernel_launch(void* const* d_in, const int* in_sizes, int n_in,
                              void* d_out, int out_size, void* d_ws, size_t ws_size,
                              hipStream_t stream) {
  const float* x    = (const float*)d_in[0];
  const float* W    = (const float*)d_in[1];
  const float* bias = (const float*)d_in[2];
  float* out   = (float*)d_out;
  float* xd    = (float*)d_ws;
  float* wsout = xd + (size_t)S * S * NB;

  (void)in_sizes; (void)n_in; (void)out_size; (void)ws_size;

  gather_x_kernel<<<dim3(S), 256, 0, stream>>>(x, xd);
  diag_linear_kernel<<<dim3(S, S / KT), 256, 0, stream>>>(xd, W, bias, wsout);
  scatter_out_kernel<<<dim3(S), 256, 0, stream>>>(wsout, out);
  tail_copy_kernel<<<dim3((NB * S * S) / 256), 256, 0, stream>>>(x, out);
}